// Round 3
// baseline (458.220 us; speedup 1.0000x reference)
//
#include <hip/hip_runtime.h>
#include <cstdint>

typedef __bf16 bf16x8 __attribute__((ext_vector_type(8)));
typedef float f32x4 __attribute__((ext_vector_type(4)));
typedef unsigned short us8 __attribute__((ext_vector_type(8)));

__device__ __forceinline__ unsigned short f2bf(float f) {
  union { float f; uint32_t u; } c; c.f = f;
  uint32_t u = c.u + 0x7FFFu + ((c.u >> 16) & 1u);
  return (unsigned short)(u >> 16);
}

// ---------------------------------------------------------------- convert
__global__ __launch_bounds__(256) void cvt5(
    const float* __restrict__ x1, const float* __restrict__ x2,
    const float* __restrict__ Wq, const float* __restrict__ Wk, const float* __restrict__ Wv,
    unsigned short* __restrict__ xb1, unsigned short* __restrict__ xb2,
    unsigned short* __restrict__ wb) {
  int z = blockIdx.y;
  const float* src; unsigned short* dst; int n4;
  if (z == 0)      { src = x1; dst = xb1;            n4 = 16777216 / 4; }
  else if (z == 1) { src = x2; dst = xb2;            n4 = 16777216 / 4; }
  else if (z == 2) { src = Wq; dst = wb;             n4 = 1048576 / 4; }
  else if (z == 3) { src = Wk; dst = wb + 1048576;   n4 = 1048576 / 4; }
  else             { src = Wv; dst = wb + 2*1048576; n4 = 1048576 / 4; }
  for (int i = blockIdx.x * 256 + threadIdx.x; i < n4; i += gridDim.x * 256) {
    float4 v = ((const float4*)src)[i];
    ushort4 o;
    o.x = f2bf(v.x); o.y = f2bf(v.y); o.z = f2bf(v.z); o.w = f2bf(v.w);
    ((ushort4*)dst)[i] = o;
  }
}

// ---------------------------------------------------------------- GEMM
// C[m,n] = sum_k A[m,k]*W[n,k] + bias[n];  M=16384, N=K=1024; bf16 in/out, fp32 acc.
// XCD swizzle (R2, kept): m-tile owned by one XCD; A HBM-fetched once, L2-served 8x.
// R3 change: A-operand bypasses LDS — each lane's A-fragment is 16 contiguous
// bytes in global (row-major, k fastest), loaded global->VGPR directly. LDS
// stages only B. LDS pipe per K-iter: 16 b128 = 128 cyc vs MFMA 77 cyc
// (was 256 cyc -> 30% MfmaUtil ceiling; now ~60%).
__global__ __launch_bounds__(256) void gemm_qkv(
    const unsigned short* __restrict__ xb1, const unsigned short* __restrict__ xb2,
    const unsigned short* __restrict__ wb,
    const float* __restrict__ bq, const float* __restrict__ bk, const float* __restrict__ bv,
    unsigned short* __restrict__ qkv) {
  __shared__ __attribute__((aligned(16))) unsigned short lB[128 * 32];
  const int id = blockIdx.x;
  const int xcd = id & 7;
  const int j = id >> 3;
  const int nb = j & 7;
  const int g = j >> 3;
  const int z = g >> 4;
  const int mb = (g & 15) * 8 + xcd;
  const unsigned short* A = (z == 0) ? xb1 : xb2;
  const unsigned short* W = wb + z * 1048576;
  const float* bias = (z == 0) ? bq : (z == 1 ? bk : bv);
  unsigned short* C = qkv + z * 16777216;
  const int n0 = nb * 128;
  const int m0 = mb * 128;
  const int lane = threadIdx.x & 63;
  const int wv = threadIdx.x >> 6;
  const int wm = wv >> 1, wn = wv & 1;
  const int mr = lane & 15, quad = lane >> 4;

  // per-lane A base: row m0 + wm*64 + mr, k offset quad*8 (i adds i*16 rows)
  const unsigned short* Abase = A + (size_t)(m0 + wm * 64 + mr) * 1024 + quad * 8;

  f32x4 acc[4][4];
#pragma unroll
  for (int i = 0; i < 4; ++i)
#pragma unroll
    for (int jj = 0; jj < 4; ++jj) acc[i][jj] = (f32x4){0.f, 0.f, 0.f, 0.f};

  for (int k0 = 0; k0 < 1024; k0 += 32) {
    // stage B(128x32): 8 chunks of 1KB, 2 per wave
#pragma unroll
    for (int c2 = 0; c2 < 2; ++c2) {
      int cc = wv * 2 + c2;
      int row = cc * 16 + (lane >> 2);
      const unsigned short* src = W + (n0 + row) * 1024 + k0;
      const char* gp = (const char*)src + (lane & 3) * 16;
      char* ldst = (char*)lB + cc * 1024;
      __builtin_amdgcn_global_load_lds((const __attribute__((address_space(1))) void*)gp,
                                       (__attribute__((address_space(3))) void*)ldst,
                                       16, 0, 0);
    }
    // A-fragments direct from global (issue before the barrier; drained with it)
    bf16x8 af[4];
#pragma unroll
    for (int i = 0; i < 4; ++i)
      af[i] = *(const bf16x8*)(Abase + (size_t)i * 16 * 1024 + k0);
    __syncthreads();
    bf16x8 bfr[4];
#pragma unroll
    for (int jj = 0; jj < 4; ++jj)
      bfr[jj] = *(const bf16x8*)(lB + (wn * 64 + jj * 16 + mr) * 32 + quad * 8);
#pragma unroll
    for (int i = 0; i < 4; ++i)
#pragma unroll
      for (int jj = 0; jj < 4; ++jj)
        acc[i][jj] = __builtin_amdgcn_mfma_f32_16x16x32_bf16(af[i], bfr[jj], acc[i][jj], 0, 0, 0);
    __syncthreads();
  }
  // epilogue: +bias, bf16 store.  D: row=quad*4+r, col=mr
#pragma unroll
  for (int jj = 0; jj < 4; ++jj) {
    int col = n0 + wn * 64 + jj * 16 + mr;
    float bb = bias[col];
#pragma unroll
    for (int i = 0; i < 4; ++i) {
      int rbase = m0 + wm * 64 + i * 16 + quad * 4;
#pragma unroll
      for (int r = 0; r < 4; ++r)
        C[(rbase + r) * 1024 + col] = f2bf(acc[i][jj][r] + bb);
    }
  }
}

// ---------------------------------------------------------------- attention
__global__ __launch_bounds__(256) void attn(const unsigned short* __restrict__ qkv,
                                            float* __restrict__ obuf) {
  const unsigned short* qbuf = qkv;
  const unsigned short* kbuf = qkv + 16777216;
  const unsigned short* vbuf = qkv + 2 * 16777216;
  __shared__ __attribute__((aligned(16))) unsigned short qs[8192];      // [t][m][dy]
  __shared__ __attribute__((aligned(16))) unsigned short ks[4][1024];   // per-wave [t][l]
  __shared__ __attribute__((aligned(16))) unsigned short vs[4][1024];   // per-wave [m][t]
  __shared__ __attribute__((aligned(16))) unsigned short ats[4][1024];  // per-wave [t][l]
  const int y0 = blockIdx.x * 8;
  const int x = blockIdx.y;
  const int b = blockIdx.z;
  const int lane = threadIdx.x & 63;
  const int wv = threadIdx.x >> 6;
  const int mr = lane & 15, quad = lane >> 4;

#pragma unroll
  for (int it = 0; it < 4; ++it) {
    int c = threadIdx.x + 256 * it;
    int t = c >> 5, m = c & 31;
    const uint4* src = (const uint4*)(qbuf + ((b * 1024 + t * 32 + x) * 1024 + m * 32 + y0));
    ((uint4*)qs)[c] = *src;
  }
  __syncthreads();

  for (int s = 0; s < 2; ++s) {
    int y = y0 + wv * 2 + s;
    int dy = wv * 2 + s;
    const unsigned short* krow = kbuf + ((b * 32 + x) * 32 + y) * 1024;
    const unsigned short* vrow = vbuf + ((b * 32 + x) * 32 + y) * 1024;
    ((uint4*)ks[wv])[lane] = ((const uint4*)krow)[lane];
    ((uint4*)ks[wv])[64 + lane] = ((const uint4*)krow)[64 + lane];
    ((uint4*)vs[wv])[lane] = ((const uint4*)vrow)[lane];
    ((uint4*)vs[wv])[64 + lane] = ((const uint4*)vrow)[64 + lane];

    bf16x8 qa[2], kb[2];
#pragma unroll
    for (int mt = 0; mt < 2; ++mt) {
      us8 tmp;
#pragma unroll
      for (int jj = 0; jj < 8; ++jj)
        tmp[jj] = qs[((quad * 8 + jj) * 32 + mt * 16 + mr) * 8 + dy];
      qa[mt] = __builtin_bit_cast(bf16x8, tmp);
    }
#pragma unroll
    for (int lt = 0; lt < 2; ++lt) {
      us8 tmp;
#pragma unroll
      for (int jj = 0; jj < 8; ++jj)
        tmp[jj] = ks[wv][(quad * 8 + jj) * 32 + lt * 16 + mr];
      kb[lt] = __builtin_bit_cast(bf16x8, tmp);
    }
    f32x4 e[2][2];
#pragma unroll
    for (int mt = 0; mt < 2; ++mt)
#pragma unroll
      for (int lt = 0; lt < 2; ++lt) {
        f32x4 zz = (f32x4){0.f, 0.f, 0.f, 0.f};
        e[mt][lt] = __builtin_amdgcn_mfma_f32_16x16x32_bf16(qa[mt], kb[lt], zz, 0, 0, 0);
      }

#pragma unroll
    for (int mt = 0; mt < 2; ++mt)
#pragma unroll
      for (int r = 0; r < 4; ++r) {
        float v0 = e[mt][0][r], v1 = e[mt][1][r];
        float mx = fmaxf(v0, v1);
#pragma unroll
        for (int off = 1; off < 16; off <<= 1) mx = fmaxf(mx, __shfl_xor(mx, off));
        float p0 = __expf(v0 - mx), p1 = __expf(v1 - mx);
        float sm = p0 + p1;
#pragma unroll
        for (int off = 1; off < 16; off <<= 1) sm += __shfl_xor(sm, off);
        float inv = 1.0f / sm;
        p0 *= inv; p1 *= inv;
        int trow = mt * 16 + quad * 4 + r;
        ats[wv][trow * 32 + mr] = f2bf(p0);
        ats[wv][trow * 32 + 16 + mr] = f2bf(p1);
      }

    bf16x8 va[2], pb[2];
#pragma unroll
    for (int i = 0; i < 2; ++i)
      va[i] = *(const bf16x8*)(&vs[wv][(i * 16 + mr) * 32 + quad * 8]);
#pragma unroll
    for (int lt = 0; lt < 2; ++lt) {
      us8 tmp;
#pragma unroll
      for (int jj = 0; jj < 8; ++jj)
        tmp[jj] = ats[wv][(quad * 8 + jj) * 32 + lt * 16 + mr];
      pb[lt] = __builtin_bit_cast(bf16x8, tmp);
    }
    f32x4 o[2][2];
#pragma unroll
    for (int i = 0; i < 2; ++i)
#pragma unroll
      for (int lt = 0; lt < 2; ++lt) {
        f32x4 zz = (f32x4){0.f, 0.f, 0.f, 0.f};
        o[i][lt] = __builtin_amdgcn_mfma_f32_16x16x32_bf16(va[i], pb[lt], zz, 0, 0, 0);
      }

    float* orow = obuf + ((b * 32 + x) * 32 + y) * 1024;
#pragma unroll
    for (int i = 0; i < 2; ++i)
#pragma unroll
      for (int lt = 0; lt < 2; ++lt)
#pragma unroll
        for (int r = 0; r < 4; ++r)
          orow[(i * 16 + quad * 4 + r) * 32 + lt * 16 + mr] = o[i][lt][r];
  }
}

// ---------------------------------------------------------------- final permute
// out[((b*32+y)*32+l)*1024 + m*32 + x] = obuf[((b*32+x)*32+y)*1024 + m*32 + l]
// R3: 8 m-tiles per block (was 1) — 2048 blocks instead of 16384 (launch-overhead).
__global__ __launch_bounds__(256) void transpose2(const float* __restrict__ obuf,
                                                  float* __restrict__ out) {
  __shared__ float t[2][32][33];
  const int y = blockIdx.y, b = blockIdx.z;
  int l = threadIdx.x & 31;
  int g = threadIdx.x >> 5;  // 8 groups
#pragma unroll
  for (int mi = 0; mi < 8; ++mi) {
    int m = blockIdx.x * 8 + mi;
    int buf = mi & 1;
    for (int xx = g; xx < 32; xx += 8)
      t[buf][xx][l] = obuf[((b * 32 + xx) * 32 + y) * 1024 + m * 32 + l];
    __syncthreads();
    for (int ll = g; ll < 32; ll += 8)
      out[((b * 32 + y) * 32 + ll) * 1024 + m * 32 + l] = t[buf][l][ll];
    // no second sync: next iter writes the other buffer; reads of that buffer
    // (2 iters ago) are fenced by the sync above
  }
}

// ---------------------------------------------------------------- launch
extern "C" void kernel_launch(void* const* d_in, const int* in_sizes, int n_in,
                              void* d_out, int out_size, void* d_ws, size_t ws_size,
                              hipStream_t stream) {
  const float* x1 = (const float*)d_in[0];
  const float* x2 = (const float*)d_in[1];
  const float* Wq = (const float*)d_in[2];
  const float* bq = (const float*)d_in[3];
  const float* Wk = (const float*)d_in[4];
  const float* bk = (const float*)d_in[5];
  const float* Wv = (const float*)d_in[6];
  const float* bv = (const float*)d_in[7];
  float* out = (float*)d_out;

  char* ws = (char*)d_ws;
  unsigned short* xb1 = (unsigned short*)ws;        // 16.7M bf16
  unsigned short* xb2 = xb1 + 16777216;             // 16.7M bf16
  unsigned short* wb = xb2 + 16777216;              // 3M bf16
  unsigned short* qkv = wb + 3 * 1048576;           // 50.3M bf16
  float* obuf = (float*)ws;                         // fp32, aliases xb1/xb2 (dead after GEMM)

  cvt5<<<dim3(2048, 5), 256, 0, stream>>>(x1, x2, Wq, Wk, Wv, xb1, xb2, wb);
  gemm_qkv<<<dim3(3072), 256, 0, stream>>>(xb1, xb2, wb, bq, bk, bv, qkv);
  attn<<<dim3(4, 32, 16), 256, 0, stream>>>(qkv, obuf);
  transpose2<<<dim3(4, 32, 16), 256, 0, stream>>>(obuf, out);
}

// Round 4
// 360.870 us; speedup vs baseline: 1.2698x; 1.2698x over previous
//
#include <hip/hip_runtime.h>
#include <cstdint>

typedef __bf16 bf16x8 __attribute__((ext_vector_type(8)));
typedef float f32x4 __attribute__((ext_vector_type(4)));
typedef unsigned short us8 __attribute__((ext_vector_type(8)));

__device__ __forceinline__ unsigned short f2bf(float f) {
  union { float f; uint32_t u; } c; c.f = f;
  uint32_t u = c.u + 0x7FFFu + ((c.u >> 16) & 1u);
  return (unsigned short)(u >> 16);
}

// ---------------------------------------------------------------- convert
__global__ __launch_bounds__(256) void cvt5(
    const float* __restrict__ x1, const float* __restrict__ x2,
    const float* __restrict__ Wq, const float* __restrict__ Wk, const float* __restrict__ Wv,
    unsigned short* __restrict__ xb1, unsigned short* __restrict__ xb2,
    unsigned short* __restrict__ wb) {
  int z = blockIdx.y;
  const float* src; unsigned short* dst; int n4;
  if (z == 0)      { src = x1; dst = xb1;            n4 = 16777216 / 4; }
  else if (z == 1) { src = x2; dst = xb2;            n4 = 16777216 / 4; }
  else if (z == 2) { src = Wq; dst = wb;             n4 = 1048576 / 4; }
  else if (z == 3) { src = Wk; dst = wb + 1048576;   n4 = 1048576 / 4; }
  else             { src = Wv; dst = wb + 2*1048576; n4 = 1048576 / 4; }
  for (int i = blockIdx.x * 256 + threadIdx.x; i < n4; i += gridDim.x * 256) {
    float4 v = ((const float4*)src)[i];
    ushort4 o;
    o.x = f2bf(v.x); o.y = f2bf(v.y); o.z = f2bf(v.z); o.w = f2bf(v.w);
    ((ushort4*)dst)[i] = o;
  }
}

// ---------------------------------------------------------------- GEMM (R2 kernel, verbatim revert)
// C[m,n] = sum_k A[m,k]*W[n,k] + bias[n];  M=16384, N=K=1024; bf16 in/out, fp32 acc.
// m97 structure + XCD swizzle. Measured 137us / 750 TF — at the m97 structural
// plateau for K=1024. R3's A-bypass-LDS regressed (TA-slow 16-line gather +
// vmcnt dependency at low occupancy); reverted.
__global__ __launch_bounds__(256) void gemm_qkv(
    const unsigned short* __restrict__ xb1, const unsigned short* __restrict__ xb2,
    const unsigned short* __restrict__ wb,
    const float* __restrict__ bq, const float* __restrict__ bk, const float* __restrict__ bv,
    unsigned short* __restrict__ qkv) {
  __shared__ __attribute__((aligned(16))) unsigned short lA[128 * 32];
  __shared__ __attribute__((aligned(16))) unsigned short lB[128 * 32];
  const int id = blockIdx.x;
  const int xcd = id & 7;
  const int j = id >> 3;
  const int nb = j & 7;
  const int g = j >> 3;
  const int z = g >> 4;
  const int mb = (g & 15) * 8 + xcd;
  const unsigned short* A = (z == 0) ? xb1 : xb2;
  const unsigned short* W = wb + z * 1048576;
  const float* bias = (z == 0) ? bq : (z == 1 ? bk : bv);
  unsigned short* C = qkv + z * 16777216;
  const int n0 = nb * 128;
  const int m0 = mb * 128;
  const int lane = threadIdx.x & 63;
  const int wv = threadIdx.x >> 6;
  const int wm = wv >> 1, wn = wv & 1;
  const int mr = lane & 15, quad = lane >> 4;

  f32x4 acc[4][4];
#pragma unroll
  for (int i = 0; i < 4; ++i)
#pragma unroll
    for (int jj = 0; jj < 4; ++jj) acc[i][jj] = (f32x4){0.f, 0.f, 0.f, 0.f};

  for (int k0 = 0; k0 < 1024; k0 += 32) {
#pragma unroll
    for (int c4 = 0; c4 < 4; ++c4) {
      int c = wv * 4 + c4;
      int isB = c >> 3;
      int cc = c & 7;
      int row = cc * 16 + (lane >> 2);
      const unsigned short* src = isB ? (W + (n0 + row) * 1024 + k0)
                                      : (A + (m0 + row) * 1024 + k0);
      const char* gp = (const char*)src + (lane & 3) * 16;
      char* ldst = (char*)(isB ? lB : lA) + cc * 1024;
      __builtin_amdgcn_global_load_lds((const __attribute__((address_space(1))) void*)gp,
                                       (__attribute__((address_space(3))) void*)ldst,
                                       16, 0, 0);
    }
    __syncthreads();
    bf16x8 af[4], bfr[4];
#pragma unroll
    for (int i = 0; i < 4; ++i)
      af[i] = *(const bf16x8*)(lA + (wm * 64 + i * 16 + mr) * 32 + quad * 8);
#pragma unroll
    for (int jj = 0; jj < 4; ++jj)
      bfr[jj] = *(const bf16x8*)(lB + (wn * 64 + jj * 16 + mr) * 32 + quad * 8);
#pragma unroll
    for (int i = 0; i < 4; ++i)
#pragma unroll
      for (int jj = 0; jj < 4; ++jj)
        acc[i][jj] = __builtin_amdgcn_mfma_f32_16x16x32_bf16(af[i], bfr[jj], acc[i][jj], 0, 0, 0);
    __syncthreads();
  }
#pragma unroll
  for (int jj = 0; jj < 4; ++jj) {
    int col = n0 + wn * 64 + jj * 16 + mr;
    float bb = bias[col];
#pragma unroll
    for (int i = 0; i < 4; ++i) {
      int rbase = m0 + wm * 64 + i * 16 + quad * 4;
#pragma unroll
      for (int r = 0; r < 4; ++r)
        C[(rbase + r) * 1024 + col] = f2bf(acc[i][jj][r] + bb);
    }
  }
}

// ---------------------------------------------------------------- attention
// R4: XCD-aware flat grid. Blocks {id, id+8, id+16, id+24} are the 4 y-octets
// of one (b,x): same mod-8 class -> same XCD, adjacent in its queue. The Q-slab
// lines (64B each, 16B used per block) are fetched once into that XCD's L2 and
// served 4x -> Q HBM traffic 134MB -> ~34MB.
__global__ __launch_bounds__(256) void attn(const unsigned short* __restrict__ qkv,
                                            float* __restrict__ obuf) {
  const unsigned short* qbuf = qkv;
  const unsigned short* kbuf = qkv + 16777216;
  const unsigned short* vbuf = qkv + 2 * 16777216;
  __shared__ __attribute__((aligned(16))) unsigned short qs[8192];      // [t][m][dy]
  __shared__ __attribute__((aligned(16))) unsigned short ks[4][1024];   // per-wave [t][l]
  __shared__ __attribute__((aligned(16))) unsigned short vs[4][1024];   // per-wave [m][t]
  __shared__ __attribute__((aligned(16))) unsigned short ats[4][1024];  // per-wave [t][l]
  const int id = blockIdx.x;
  const int xcd = id & 7;
  const int pos = id >> 3;
  const int y0 = (pos & 3) * 8;
  const int bx = (pos >> 2) * 8 + xcd;   // 0..511
  const int b = bx >> 5;
  const int x = bx & 31;
  const int lane = threadIdx.x & 63;
  const int wv = threadIdx.x >> 6;
  const int mr = lane & 15, quad = lane >> 4;

#pragma unroll
  for (int it = 0; it < 4; ++it) {
    int c = threadIdx.x + 256 * it;
    int t = c >> 5, m = c & 31;
    const uint4* src = (const uint4*)(qbuf + ((b * 1024 + t * 32 + x) * 1024 + m * 32 + y0));
    ((uint4*)qs)[c] = *src;
  }
  __syncthreads();

  for (int s = 0; s < 2; ++s) {
    int y = y0 + wv * 2 + s;
    int dy = wv * 2 + s;
    const unsigned short* krow = kbuf + ((b * 32 + x) * 32 + y) * 1024;
    const unsigned short* vrow = vbuf + ((b * 32 + x) * 32 + y) * 1024;
    ((uint4*)ks[wv])[lane] = ((const uint4*)krow)[lane];
    ((uint4*)ks[wv])[64 + lane] = ((const uint4*)krow)[64 + lane];
    ((uint4*)vs[wv])[lane] = ((const uint4*)vrow)[lane];
    ((uint4*)vs[wv])[64 + lane] = ((const uint4*)vrow)[64 + lane];

    bf16x8 qa[2], kb[2];
#pragma unroll
    for (int mt = 0; mt < 2; ++mt) {
      us8 tmp;
#pragma unroll
      for (int jj = 0; jj < 8; ++jj)
        tmp[jj] = qs[((quad * 8 + jj) * 32 + mt * 16 + mr) * 8 + dy];
      qa[mt] = __builtin_bit_cast(bf16x8, tmp);
    }
#pragma unroll
    for (int lt = 0; lt < 2; ++lt) {
      us8 tmp;
#pragma unroll
      for (int jj = 0; jj < 8; ++jj)
        tmp[jj] = ks[wv][(quad * 8 + jj) * 32 + lt * 16 + mr];
      kb[lt] = __builtin_bit_cast(bf16x8, tmp);
    }
    f32x4 e[2][2];
#pragma unroll
    for (int mt = 0; mt < 2; ++mt)
#pragma unroll
      for (int lt = 0; lt < 2; ++lt) {
        f32x4 zz = (f32x4){0.f, 0.f, 0.f, 0.f};
        e[mt][lt] = __builtin_amdgcn_mfma_f32_16x16x32_bf16(qa[mt], kb[lt], zz, 0, 0, 0);
      }

#pragma unroll
    for (int mt = 0; mt < 2; ++mt)
#pragma unroll
      for (int r = 0; r < 4; ++r) {
        float v0 = e[mt][0][r], v1 = e[mt][1][r];
        float mx = fmaxf(v0, v1);
#pragma unroll
        for (int off = 1; off < 16; off <<= 1) mx = fmaxf(mx, __shfl_xor(mx, off));
        float p0 = __expf(v0 - mx), p1 = __expf(v1 - mx);
        float sm = p0 + p1;
#pragma unroll
        for (int off = 1; off < 16; off <<= 1) sm += __shfl_xor(sm, off);
        float inv = 1.0f / sm;
        p0 *= inv; p1 *= inv;
        int trow = mt * 16 + quad * 4 + r;
        ats[wv][trow * 32 + mr] = f2bf(p0);
        ats[wv][trow * 32 + 16 + mr] = f2bf(p1);
      }

    bf16x8 va[2], pb[2];
#pragma unroll
    for (int i = 0; i < 2; ++i)
      va[i] = *(const bf16x8*)(&vs[wv][(i * 16 + mr) * 32 + quad * 8]);
#pragma unroll
    for (int lt = 0; lt < 2; ++lt) {
      us8 tmp;
#pragma unroll
      for (int jj = 0; jj < 8; ++jj)
        tmp[jj] = ats[wv][(quad * 8 + jj) * 32 + lt * 16 + mr];
      pb[lt] = __builtin_bit_cast(bf16x8, tmp);
    }
    f32x4 o[2][2];
#pragma unroll
    for (int i = 0; i < 2; ++i)
#pragma unroll
      for (int lt = 0; lt < 2; ++lt) {
        f32x4 zz = (f32x4){0.f, 0.f, 0.f, 0.f};
        o[i][lt] = __builtin_amdgcn_mfma_f32_16x16x32_bf16(va[i], pb[lt], zz, 0, 0, 0);
      }

    float* orow = obuf + ((b * 32 + x) * 32 + y) * 1024;
#pragma unroll
    for (int i = 0; i < 2; ++i)
#pragma unroll
      for (int lt = 0; lt < 2; ++lt)
#pragma unroll
        for (int r = 0; r < 4; ++r)
          orow[(i * 16 + quad * 4 + r) * 32 + lt * 16 + mr] = o[i][lt][r];
  }
}

// ---------------------------------------------------------------- final permute
// out[((b*32+y)*32+l)*1024 + m*32 + x] = obuf[((b*32+x)*32+y)*1024 + m*32 + l]
__global__ __launch_bounds__(256) void transpose2(const float* __restrict__ obuf,
                                                  float* __restrict__ out) {
  __shared__ float t[2][32][33];
  const int y = blockIdx.y, b = blockIdx.z;
  int l = threadIdx.x & 31;
  int g = threadIdx.x >> 5;
#pragma unroll
  for (int mi = 0; mi < 8; ++mi) {
    int m = blockIdx.x * 8 + mi;
    int buf = mi & 1;
    for (int xx = g; xx < 32; xx += 8)
      t[buf][xx][l] = obuf[((b * 32 + xx) * 32 + y) * 1024 + m * 32 + l];
    __syncthreads();
    for (int ll = g; ll < 32; ll += 8)
      out[((b * 32 + y) * 32 + ll) * 1024 + m * 32 + l] = t[buf][l][ll];
  }
}

// ---------------------------------------------------------------- launch
extern "C" void kernel_launch(void* const* d_in, const int* in_sizes, int n_in,
                              void* d_out, int out_size, void* d_ws, size_t ws_size,
                              hipStream_t stream) {
  const float* x1 = (const float*)d_in[0];
  const float* x2 = (const float*)d_in[1];
  const float* Wq = (const float*)d_in[2];
  const float* bq = (const float*)d_in[3];
  const float* Wk = (const float*)d_in[4];
  const float* bk = (const float*)d_in[5];
  const float* Wv = (const float*)d_in[6];
  const float* bv = (const float*)d_in[7];
  float* out = (float*)d_out;

  char* ws = (char*)d_ws;
  unsigned short* xb1 = (unsigned short*)ws;
  unsigned short* xb2 = xb1 + 16777216;
  unsigned short* wb = xb2 + 16777216;
  unsigned short* qkv = wb + 3 * 1048576;
  float* obuf = (float*)ws;  // aliases xb1/xb2 (dead after GEMM)

  cvt5<<<dim3(2048, 5), 256, 0, stream>>>(x1, x2, Wq, Wk, Wv, xb1, xb2, wb);
  gemm_qkv<<<dim3(3072), 256, 0, stream>>>(xb1, xb2, wb, bq, bk, bv, qkv);
  attn<<<dim3(2048), 256, 0, stream>>>(qkv, obuf);
  transpose2<<<dim3(4, 32, 16), 256, 0, stream>>>(obuf, out);
}